// Round 11
// baseline (258.699 us; speedup 1.0000x reference)
//
#include <hip/hip_runtime.h>

// Problem constants (mirror the reference)
#define EMB      200000
#define DIM      256
#define WALK     80
#define WIN      5
#define BATCH    32
#define PPW      770                 // positive pairs per walk
#define NPOSN    (BATCH * PPW)       // 24640 positive pairs
#define NNEG     (NPOSN * 5)         // 123200 negative pairs
#define NPAIR    (NPOSN + NNEG)      // 147840 pairs
#define NPOSIT   (BATCH * WALK)      // 2560 node positions
#define LR       0.025f
#define LAP      0.01f
#define INV_STRIDE 64                // max 50 inverse hits per position

#define T4          (EMB * DIM / 4)  // 12,800,000 float4 per table
#define CHUNK_F4    2048             // 32 KB per copy block
#define COPY_CHUNKS (2 * T4 / CHUNK_F4)   // 12,500

#define INV_BLOCKS   482             // ceil(NNEG/256)
#define OWN_BLOCKS   10              // ceil(NPOSIT/256)
#define SCORE_BLOCKS (NPAIR / 4)     // 36,960 (4 waves/block, 1 pair/wave)
#define ACC_BLOCKS   1280            // 5120 waves = position-sides

typedef __attribute__((ext_vector_type(4))) int v4i;
typedef __attribute__((ext_vector_type(4))) float v4f;

// Prefix sum of per-center context counts within one walk: S(i) = sum_{k<i} c(k),
// c(k) = min(k,5) + min(79-k,5).  S(80) = 770.
__device__ __forceinline__ int Sfun(int i) {
    if (i <= 5)  return 5 * i + (i * (i - 1)) / 2;
    if (i <= 75) return 35 + 10 * (i - 5);
    return 735 + (i - 75) * 84 - ((i + 74) * (i - 75)) / 2;
}

__device__ __forceinline__ float wave_sum(float s) {
#pragma unroll
    for (int off = 32; off > 0; off >>= 1) s += __shfl_xor(s, off, 64);
    return s;
}

__device__ __forceinline__ float fast_sig(const float* __restrict__ t, float d) {
    float s = fminf(fmaxf(d, -6.0f), 6.0f);
    int idx = (int)floorf((s + 6.01f) / 0.01f);
    return t[idx];
}

// Stage the 2560 touched rows into compact ws buffers; zero acc; mark=INT_MAX;
// zero cnt.
__global__ void __launch_bounds__(256) k_stage(
        const int* __restrict__ nodes,
        const float* __restrict__ uw,
        const float* __restrict__ vw,
        float* __restrict__ eu,
        float* __restrict__ ev,
        v4f* __restrict__ accz,      // accu+accv as float4 (327,680 v4f)
        v4i* __restrict__ markz,     // mark as int4 (50,000 v4i)
        int* __restrict__ cnt) {
    int p = blockIdx.x;
    int d = threadIdx.x;
    int node = nodes[p];
    eu[p * DIM + d] = uw[(size_t)node * DIM + d];
    ev[p * DIM + d] = vw[(size_t)node * DIM + d];
    int tid = p * 256 + d;
    if (tid < (2 * NPOSIT * DIM) / 4) accz[tid] = (v4f){0.f, 0.f, 0.f, 0.f};
    if (tid < EMB / 4) markz[tid] = (v4i){0x7FFFFFFF, 0x7FFFFFFF, 0x7FFFFFFF, 0x7FFFFFFF};
    if (d == 0) cnt[p] = 0;
}

// Inverse index of negv (blocks [0,INV_BLOCKS)); O(1) owner via atomicMin (rest).
__global__ void k_index(const int* __restrict__ negv,
                        const int* __restrict__ nodes,
                        int* __restrict__ cnt,
                        int* __restrict__ inv,
                        int* __restrict__ mark) {
    int bid = blockIdx.x;
    if (bid < INV_BLOCKS) {
        int m = bid * 256 + threadIdx.x;
        if (m < NNEG) {
            int p = negv[m];
            int slot = atomicAdd(&cnt[p], 1);
            inv[p * INV_STRIDE + slot] = m;
        }
    } else {
        int p = (bid - INV_BLOCKS) * 256 + threadIdx.x;
        if (p < NPOSIT) atomicMin(&mark[nodes[p]], p);   // owner = min position
    }
}

// One wave per pair: its sigmoid coefficient (massively parallel, one short
// chain per wave — kills the 60-segment serial chain of single-pass grad).
__global__ void __launch_bounds__(256) k_scores(
        const float* __restrict__ eu,
        const float* __restrict__ ev,
        const float* __restrict__ table,
        const int*   __restrict__ negu,
        const int*   __restrict__ negv,
        float*       __restrict__ scp,
        float*       __restrict__ scn) {
    int wid  = blockIdx.x * 4 + (threadIdx.x >> 6);   // 0..NPAIR-1
    int lane = threadIdx.x & 63;
    int col  = lane * 4;

    int ua, va, ispos;
    if (wid < NPOSN) {
        ispos = 1;
        int w = wid / PPW;
        int r = wid - w * PPW;
        int i;
        if (r < 35)       { i = 0;  while (Sfun(i + 1) <= r) ++i; }
        else if (r < 735) { i = 5 + (r - 35) / 10; }
        else              { i = 75; while (Sfun(i + 1) <= r) ++i; }
        int o    = r - Sfun(i);
        int jlo  = (i - WIN < 0) ? 0 : i - WIN;
        int nlow = i - jlo;
        int j    = (o < nlow) ? (jlo + o) : (i + 1 + o - nlow);
        ua = w * WALK + j;                 // context position (u side)
        va = w * WALK + i;                 // center position (v side)
    } else {
        ispos = 0;
        int m = wid - NPOSN;
        ua = negu[m];
        va = negv[m];
    }

    const float4 a = *(const float4*)&eu[ua * DIM + col];
    const float4 b = *(const float4*)&ev[va * DIM + col];
    float d = wave_sum(a.x * b.x + a.y * b.y + a.z * b.z + a.w * b.w);
    float sg = fast_sig(table, d);
    if (lane == 0) {
        if (ispos) scp[wid] = 1.0f - sg;
        else       scn[wid - NPOSN] = -sg;
    }
}

// One wave per (position, side): g = sum_t coeff[t]*row[t] (+ LAP terms).
// Chain-free — loads independent across iterations. Atomic into owner acc row.
__global__ void __launch_bounds__(256) k_accum(
        const int*   __restrict__ nodes,
        const float* __restrict__ eu,
        const float* __restrict__ ev,
        const float* __restrict__ scp,
        const float* __restrict__ scn,
        const int*   __restrict__ negu,
        const int*   __restrict__ negv,
        const int*   __restrict__ cnt,
        const int*   __restrict__ inv,
        const int*   __restrict__ mark,
        float*       __restrict__ accu,
        float*       __restrict__ accv) {
    int wid  = blockIdx.x * 4 + (threadIdx.x >> 6);   // 0..5119
    int lane = threadIdx.x & 63;
    int side = wid >= NPOSIT;
    int p    = side ? wid - NPOSIT : wid;
    int w    = p / WALK;
    int i    = p - w * WALK;
    int col  = lane * 4;

    int jlo = (i - WIN < 0) ? 0 : i - WIN;
    int jhi = (i + WIN > WALK - 1) ? WALK - 1 : i + WIN;
    int Si  = Sfun(i);
    int ci  = Sfun(i + 1) - Si;
    int own = mark[nodes[p]];

    float gx = 0.f, gy = 0.f, gz = 0.f, gw = 0.f;

    if (!side) {
        // grad_u[p]: p is the context; centers c in win(p).
        const float4 mu = *(const float4*)&eu[p * DIM + col];
        for (int c = jlo; c <= jhi; ++c) {
            if (c == i) continue;
            int jloc = (c - WIN < 0) ? 0 : c - WIN;
            int nlow = c - jloc;
            int off  = (i < c) ? (i - jloc) : (nlow + i - c - 1);
            float coeff = scp[w * PPW + Sfun(c) + off];
            float4 row = *(const float4*)&ev[(w * WALK + c) * DIM + col];
            gx += coeff * row.x + LAP * (row.x - mu.x);
            gy += coeff * row.y + LAP * (row.y - mu.y);
            gz += coeff * row.z + LAP * (row.z - mu.z);
            gw += coeff * row.w + LAP * (row.w - mu.w);
        }
        int mstart = 5 * (PPW * w + Si);
        int mcnt   = 5 * ci;
        for (int t = 0; t < mcnt; ++t) {
            int m = mstart + t;
            int z = negv[m];
            float c = scn[m];
            float4 row = *(const float4*)&ev[z * DIM + col];
            gx += c * row.x; gy += c * row.y; gz += c * row.z; gw += c * row.w;
        }
        float* dst = &accu[(size_t)own * DIM + col];
        atomicAdd(dst + 0, gx);
        atomicAdd(dst + 1, gy);
        atomicAdd(dst + 2, gz);
        atomicAdd(dst + 3, gw);
    } else {
        // grad_v[p]: p is the center; contexts j enumerated in pair order.
        const float4 mv = *(const float4*)&ev[p * DIM + col];
        int nlow = i - jlo;
        for (int t = 0; t < ci; ++t) {
            int j = (t < nlow) ? (jlo + t) : (i + 1 + t - nlow);
            float coeff = scp[w * PPW + Si + t];
            float4 row = *(const float4*)&eu[(w * WALK + j) * DIM + col];
            gx += coeff * row.x + LAP * (row.x - mv.x);
            gy += coeff * row.y + LAP * (row.y - mv.y);
            gz += coeff * row.z + LAP * (row.z - mv.z);
            gw += coeff * row.w + LAP * (row.w - mv.w);
        }
        int ninv = cnt[p];
        for (int t = 0; t < ninv; ++t) {
            int m = inv[p * INV_STRIDE + t];
            int a = negu[m];
            float c = scn[m];
            float4 row = *(const float4*)&eu[a * DIM + col];
            gx += c * row.x; gy += c * row.y; gz += c * row.z; gw += c * row.w;
        }
        float* dst = &accv[(size_t)own * DIM + col];
        atomicAdd(dst + 0, gx);
        atomicAdd(dst + 1, gy);
        atomicAdd(dst + 2, gz);
        atomicAdd(dst + 3, gw);
    }
}

// Plain chunked copy — no mark reads, pure stream (isolates the copy rate).
__global__ void __launch_bounds__(256) k_copy(const float* __restrict__ uw,
                                              const float* __restrict__ vw,
                                              float* __restrict__ out) {
    size_t base = (size_t)blockIdx.x * CHUNK_F4;
    int tbl = base >= (size_t)T4;
    const float4* __restrict__ src = tbl ? (const float4*)vw : (const float4*)uw;
    size_t soff = tbl ? base - T4 : base;
    float4* __restrict__ dst = (float4*)out + base;
    int t = threadIdx.x;
#pragma unroll
    for (int k = 0; k < CHUNK_F4 / 256; ++k)
        dst[t + k * 256] = src[soff + t + k * 256];
}

// Owned rows (~2544 per table) overwritten with w + LR*acc (direct store).
__global__ void k_fix(const int* __restrict__ nodes,
                      const float* __restrict__ uw,
                      const float* __restrict__ vw,
                      const float* __restrict__ accu,
                      const float* __restrict__ accv,
                      const int* __restrict__ mark,
                      float* __restrict__ out) {
    int p = blockIdx.x;
    int n = nodes[p];
    if (mark[n] != p) return;         // only the owner writes
    int d = threadIdx.x;
    size_t off = (size_t)n * DIM + d;
    out[off] = uw[off] + LR * accu[(size_t)p * DIM + d];
    out[(size_t)EMB * DIM + off] = vw[off] + LR * accv[(size_t)p * DIM + d];
}

extern "C" void kernel_launch(void* const* d_in, const int* in_sizes, int n_in,
                              void* d_out, int out_size, void* d_ws, size_t ws_size,
                              hipStream_t stream) {
    const int*   nodes = (const int*)d_in[0];
    const float* uw    = (const float*)d_in[1];
    const float* vw    = (const float*)d_in[2];
    const float* table = (const float*)d_in[3];
    // d_in[4] = idx_posu, d_in[5] = idx_posv (window is analytic)
    const int*   negu  = (const int*)d_in[6];
    const int*   negv  = (const int*)d_in[7];
    float* out = (float*)d_out;

    // ws layout: [eu | ev | accu | accv | scp | scn | cnt | inv | mark]
    float* eu    = (float*)d_ws;
    float* ev    = eu + (size_t)NPOSIT * DIM;
    float* accu  = ev + (size_t)NPOSIT * DIM;
    float* accv  = accu + (size_t)NPOSIT * DIM;       // contiguous with accu
    float* scp   = accv + (size_t)NPOSIT * DIM;
    float* scn   = scp + NPOSN;
    int*   cnt   = (int*)(scn + NNEG);
    int*   inv   = cnt + NPOSIT;
    int*   mark  = inv + (size_t)NPOSIT * INV_STRIDE; // 16B-aligned

    // 1. Stage rows; zero acc; mark=INT_MAX; zero cnt.
    k_stage<<<NPOSIT, DIM, 0, stream>>>(nodes, uw, vw, eu, ev,
                                        (v4f*)accu, (v4i*)mark, cnt);
    // 2. Inverse index + O(1) owner (atomicMin).
    k_index<<<INV_BLOCKS + OWN_BLOCKS, 256, 0, stream>>>(negv, nodes, cnt, inv, mark);
    // 3. All pair coefficients (one wave per pair).
    k_scores<<<SCORE_BLOCKS, 256, 0, stream>>>(eu, ev, table, negu, negv, scp, scn);
    // 4. Chain-free accumulation into owner acc rows.
    k_accum<<<ACC_BLOCKS, 256, 0, stream>>>(nodes, eu, ev, scp, scn, negu, negv,
                                            cnt, inv, mark, accu, accv);
    // 5. Plain streaming copy.
    k_copy<<<COPY_CHUNKS, 256, 0, stream>>>(uw, vw, out);
    // 6. Overwrite owned rows with w + LR*acc.
    k_fix<<<NPOSIT, DIM, 0, stream>>>(nodes, uw, vw, accu, accv, mark, out);
}

// Round 12
// 220.579 us; speedup vs baseline: 1.1728x; 1.1728x over previous
//
#include <hip/hip_runtime.h>

// Problem constants (mirror the reference)
#define EMB      200000
#define DIM      256
#define WALK     80
#define WIN      5
#define BATCH    32
#define PPW      770                 // positive pairs per walk
#define NPOSN    (BATCH * PPW)       // 24640 positive pairs
#define NNEG     (NPOSN * 5)         // 123200 negative pairs
#define NPOSIT   (BATCH * WALK)      // 2560 node positions
#define LR       0.025f
#define LAP      0.01f
#define INV_STRIDE 64                // max 50 inverse hits per position

#define T4          (EMB * DIM / 4)  // 12,800,000 float4 per table
#define CHUNK_F4    2048             // 32 KB per copy block
#define COPY_CHUNKS (2 * T4 / CHUNK_F4)   // 12,500

#define INV_BLOCKS  482              // ceil(NNEG/256)
#define OWN_BLOCKS  10               // ceil(NPOSIT/256)
#define GRAD_BLOCKS 1280             // 5120 waves = 5120 position-side tasks

typedef __attribute__((ext_vector_type(4))) int v4i;
typedef __attribute__((ext_vector_type(4))) float v4f;

// Prefix sum of per-center context counts within one walk: S(i) = sum_{k<i} c(k),
// c(k) = min(k,5) + min(79-k,5).  S(80) = 770.
__device__ __forceinline__ int Sfun(int i) {
    if (i <= 5)  return 5 * i + (i * (i - 1)) / 2;
    if (i <= 75) return 35 + 10 * (i - 5);
    return 735 + (i - 75) * 84 - ((i + 74) * (i - 75)) / 2;
}

__device__ __forceinline__ float wave_sum(float s) {
#pragma unroll
    for (int off = 32; off > 0; off >>= 1) s += __shfl_xor(s, off, 64);
    return s;
}

__device__ __forceinline__ float fast_sig(const float* __restrict__ t, float d) {
    float s = fminf(fmaxf(d, -6.0f), 6.0f);
    int idx = (int)floorf((s + 6.01f) / 0.01f);
    return t[idx];
}

// Stage the 2560 touched rows into compact ws buffers; zero acc; mark=INT_MAX;
// zero cnt.
__global__ void __launch_bounds__(256) k_stage(
        const int* __restrict__ nodes,
        const float* __restrict__ uw,
        const float* __restrict__ vw,
        float* __restrict__ eu,
        float* __restrict__ ev,
        v4f* __restrict__ accz,      // accu+accv as float4 (327,680 v4f)
        v4i* __restrict__ markz,     // mark as int4 (50,000 v4i)
        int* __restrict__ cnt) {
    int p = blockIdx.x;
    int d = threadIdx.x;
    int node = nodes[p];
    eu[p * DIM + d] = uw[(size_t)node * DIM + d];
    ev[p * DIM + d] = vw[(size_t)node * DIM + d];
    int tid = p * 256 + d;
    if (tid < (2 * NPOSIT * DIM) / 4) accz[tid] = (v4f){0.f, 0.f, 0.f, 0.f};
    if (tid < EMB / 4) markz[tid] = (v4i){0x7FFFFFFF, 0x7FFFFFFF, 0x7FFFFFFF, 0x7FFFFFFF};
    if (d == 0) cnt[p] = 0;
}

// Inverse index of negv (blocks [0,INV_BLOCKS)); O(1) owner via atomicMin (rest).
__global__ void k_index(const int* __restrict__ negv,
                        const int* __restrict__ nodes,
                        int* __restrict__ cnt,
                        int* __restrict__ inv,
                        int* __restrict__ mark) {
    int bid = blockIdx.x;
    if (bid < INV_BLOCKS) {
        int m = bid * 256 + threadIdx.x;
        if (m < NNEG) {
            int p = negv[m];
            int slot = atomicAdd(&cnt[p], 1);
            inv[p * INV_STRIDE + slot] = m;
        }
    } else {
        int p = (bid - INV_BLOCKS) * 256 + threadIdx.x;
        if (p < NPOSIT) atomicMin(&mark[nodes[p]], p);   // owner = min position
    }
}

// Fused kernel (R6's proven config):
//   blocks [0, GRAD_BLOCKS)             : one grad task per wave (staged reads,
//                                         owner-atomic acc into ws — no out access)
//   blocks [GRAD_BLOCKS, +COPY_CHUNKS)  : 819 MB chunked table copy into out
__global__ void __launch_bounds__(256) k_fused(
        const int*   __restrict__ nodes,
        const float* __restrict__ uw,
        const float* __restrict__ vw,
        const float* __restrict__ table,
        const int*   __restrict__ negu,
        const int*   __restrict__ negv,
        const float* __restrict__ eu,
        const float* __restrict__ ev,
        const int*   __restrict__ cnt,
        const int*   __restrict__ inv,
        const int*   __restrict__ mark,
        float*       __restrict__ accu,
        float*       __restrict__ accv,
        float*       __restrict__ out) {
    if (blockIdx.x >= GRAD_BLOCKS) {
        // ---------------- copy chunk ----------------
        size_t base = (size_t)(blockIdx.x - GRAD_BLOCKS) * CHUNK_F4;
        int tbl = base >= (size_t)T4;
        const float4* __restrict__ src = tbl ? (const float4*)vw : (const float4*)uw;
        size_t soff = tbl ? base - T4 : base;
        float4* __restrict__ dst = (float4*)out + base;
        int t = threadIdx.x;
#pragma unroll
        for (int k = 0; k < CHUNK_F4 / 256; ++k)
            dst[t + k * 256] = src[soff + t + k * 256];
        return;
    }

    // ---------------- grad: one (position, side) task per wave ----------------
    int wid  = blockIdx.x * 4 + (threadIdx.x >> 6);   // 0..5119
    int lane = threadIdx.x & 63;
    int side = wid >= NPOSIT;                         // 0: u-side, 1: v-side
    int p    = side ? wid - NPOSIT : wid;
    int b    = p / WALK;
    int i    = p - b * WALK;
    int col  = lane * 4;

    int jlo = (i - WIN < 0) ? 0 : i - WIN;
    int jhi = (i + WIN > WALK - 1) ? WALK - 1 : i + WIN;
    int own = mark[nodes[p]];                         // owner position for node

    if (!side) {
        // grad_u[p]: window pairs (u=p, v=q) + negatives where p is the center.
        const float4 mu = *(const float4*)&eu[p * DIM + col];
        float gx = 0.f, gy = 0.f, gz = 0.f, gw = 0.f;

        for (int j = jlo; j <= jhi; ++j) {
            if (j == i) continue;
            int q = b * WALK + j;
            float4 qv = *(const float4*)&ev[q * DIM + col];
            float d1 = wave_sum(mu.x * qv.x + mu.y * qv.y + mu.z * qv.z + mu.w * qv.w);
            float s1 = 1.0f - fast_sig(table, d1);
            gx += s1 * qv.x + LAP * (qv.x - mu.x);
            gy += s1 * qv.y + LAP * (qv.y - mu.y);
            gz += s1 * qv.z + LAP * (qv.z - mu.z);
            gw += s1 * qv.w + LAP * (qv.w - mu.w);
        }

        int Si = Sfun(i);
        int ci = Sfun(i + 1) - Si;
        int mstart = 5 * (PPW * b + Si);
        int mcnt   = 5 * ci;
        for (int t = 0; t < mcnt; ++t) {
            int z = negv[mstart + t];
            float4 zv = *(const float4*)&ev[z * DIM + col];
            float d  = wave_sum(mu.x * zv.x + mu.y * zv.y + mu.z * zv.z + mu.w * zv.w);
            float ns = -fast_sig(table, d);
            gx += ns * zv.x; gy += ns * zv.y; gz += ns * zv.z; gw += ns * zv.w;
        }

        float* dst = &accu[(size_t)own * DIM + col];
        atomicAdd(dst + 0, gx);
        atomicAdd(dst + 1, gy);
        atomicAdd(dst + 2, gz);
        atomicAdd(dst + 3, gw);
    } else {
        // grad_v[p]: window pairs (u=q, v=p) + negatives where p is the v target.
        const float4 mv = *(const float4*)&ev[p * DIM + col];
        float gx = 0.f, gy = 0.f, gz = 0.f, gw = 0.f;

        for (int j = jlo; j <= jhi; ++j) {
            if (j == i) continue;
            int q = b * WALK + j;
            float4 qu = *(const float4*)&eu[q * DIM + col];
            float d2 = wave_sum(qu.x * mv.x + qu.y * mv.y + qu.z * mv.z + qu.w * mv.w);
            float s2 = 1.0f - fast_sig(table, d2);
            gx += s2 * qu.x + LAP * (qu.x - mv.x);
            gy += s2 * qu.y + LAP * (qu.y - mv.y);
            gz += s2 * qu.z + LAP * (qu.z - mv.z);
            gw += s2 * qu.w + LAP * (qu.w - mv.w);
        }

        int ninv = cnt[p];
        for (int t = 0; t < ninv; ++t) {
            int m = inv[p * INV_STRIDE + t];
            int a = negu[m];
            float4 au = *(const float4*)&eu[a * DIM + col];
            float d  = wave_sum(au.x * mv.x + au.y * mv.y + au.z * mv.z + au.w * mv.w);
            float ns = -fast_sig(table, d);
            gx += ns * au.x; gy += ns * au.y; gz += ns * au.z; gw += ns * au.w;
        }

        float* dst = &accv[(size_t)own * DIM + col];
        atomicAdd(dst + 0, gx);
        atomicAdd(dst + 1, gy);
        atomicAdd(dst + 2, gz);
        atomicAdd(dst + 3, gw);
    }
}

// Owned rows (~2544 per table) overwritten with w + LR*acc (direct store, no atomics).
__global__ void k_fix(const int* __restrict__ nodes,
                      const float* __restrict__ uw,
                      const float* __restrict__ vw,
                      const float* __restrict__ accu,
                      const float* __restrict__ accv,
                      const int* __restrict__ mark,
                      float* __restrict__ out) {
    int p = blockIdx.x;
    int n = nodes[p];
    if (mark[n] != p) return;         // only the owner writes
    int d = threadIdx.x;
    size_t off = (size_t)n * DIM + d;
    out[off] = uw[off] + LR * accu[(size_t)p * DIM + d];
    out[(size_t)EMB * DIM + off] = vw[off] + LR * accv[(size_t)p * DIM + d];
}

extern "C" void kernel_launch(void* const* d_in, const int* in_sizes, int n_in,
                              void* d_out, int out_size, void* d_ws, size_t ws_size,
                              hipStream_t stream) {
    const int*   nodes = (const int*)d_in[0];
    const float* uw    = (const float*)d_in[1];
    const float* vw    = (const float*)d_in[2];
    const float* table = (const float*)d_in[3];
    // d_in[4] = idx_posu, d_in[5] = idx_posv (window is analytic)
    const int*   negu  = (const int*)d_in[6];
    const int*   negv  = (const int*)d_in[7];
    float* out = (float*)d_out;

    // ws layout: [eu | ev | accu | accv | cnt | inv | mark]
    float* eu    = (float*)d_ws;
    float* ev    = eu + (size_t)NPOSIT * DIM;
    float* accu  = ev + (size_t)NPOSIT * DIM;
    float* accv  = accu + (size_t)NPOSIT * DIM;       // contiguous with accu
    int*   cnt   = (int*)(accv + (size_t)NPOSIT * DIM);
    int*   inv   = cnt + NPOSIT;
    int*   mark  = inv + (size_t)NPOSIT * INV_STRIDE;

    // 1. Stage rows; zero acc; mark=INT_MAX; zero cnt.
    k_stage<<<NPOSIT, DIM, 0, stream>>>(nodes, uw, vw, eu, ev,
                                        (v4f*)accu, (v4i*)mark, cnt);
    // 2. Inverse index + O(1) owner (atomicMin).
    k_index<<<INV_BLOCKS + OWN_BLOCKS, 256, 0, stream>>>(negv, nodes, cnt, inv, mark);
    // 3. Fused: staged grad (ws-only atomics) overlapped with the chunked copy.
    k_fused<<<GRAD_BLOCKS + COPY_CHUNKS, 256, 0, stream>>>(
        nodes, uw, vw, table, negu, negv, eu, ev, cnt, inv, mark,
        accu, accv, out);
    // 4. Overwrite owned rows with w + LR*acc.
    k_fix<<<NPOSIT, DIM, 0, stream>>>(nodes, uw, vw, accu, accv, mark, out);
}